// Round 3
// baseline (21586.467 us; speedup 1.0000x reference)
//
#include <hip/hip_runtime.h>
#include <hip/hip_bf16.h>

#define B 64
#define SEQ 256
#define IN 512
#define HD 1024
#define ODIM 512
#define NWG 64
#define WGTH 512

typedef __attribute__((ext_vector_type(8))) short bf16x8;
typedef __attribute__((ext_vector_type(4))) float f32x4;
typedef __attribute__((ext_vector_type(4))) unsigned short u16x4;

__device__ __forceinline__ f32x4 mfma16(bf16x8 a, bf16x8 b, f32x4 c) {
  return __builtin_amdgcn_mfma_f32_16x16x32_bf16(a, b, c, 0, 0, 0);
}

__device__ __forceinline__ unsigned short f2bf(float f) {
  unsigned u = __builtin_bit_cast(unsigned, f);
  u += 0x7FFFu + ((u >> 16) & 1u);
  return (unsigned short)(u >> 16);
}

__device__ __forceinline__ float sigmoidf_(float x) { return 1.f / (1.f + expf(-x)); }

// device-scope (LLC-coherent) 16B load as 2x relaxed agent atomic b64 (emits sc1, no L2 fill)
__device__ __forceinline__ bf16x8 ld_sc(const unsigned short* p) {
  union { unsigned long long u[2]; bf16x8 v; } r;
  const unsigned long long* q = (const unsigned long long*)p;
  r.u[0] = __hip_atomic_load(q, __ATOMIC_RELAXED, __HIP_MEMORY_SCOPE_AGENT);
  r.u[1] = __hip_atomic_load(q + 1, __ATOMIC_RELAXED, __HIP_MEMORY_SCOPE_AGENT);
  return r.v;
}

// device-scope write-through 2B store (sc1: write past L2 to LLC)
__device__ __forceinline__ void st_sc16(unsigned short* p, unsigned short v) {
  unsigned vv = v;
  asm volatile("global_store_short %0, %1, off sc1" : : "v"(p), "v"(vv) : "memory");
}

// ---- x: plain f32 -> bf16 conversion (A-operand, row-major kept) ----
__global__ void f32_to_bf16_k(const float* __restrict__ s, unsigned short* __restrict__ d, int n) {
  int i = (blockIdx.x * blockDim.x + threadIdx.x) * 4;
  if (i < n) {
    float4 v = *reinterpret_cast<const float4*>(s + i);
    u16x4 o;
    o.x = f2bf(v.x); o.y = f2bf(v.y); o.z = f2bf(v.z); o.w = f2bf(v.w);
    *reinterpret_cast<u16x4*>(d + i) = o;
  }
}

// ---- weights: f32 [N][K] -> bf16 packed MFMA B-fragment layout ----
struct PackSeg { const float* s; unsigned short* d; int N; int K; };
struct PackP { PackSeg seg[13]; };

__global__ void pack_w(PackP P) {
  PackSeg sg = P.seg[blockIdx.y];
  const int kc_n = sg.K >> 5;
  const int total = (sg.N * sg.K) >> 3;
  for (int i = blockIdx.x * blockDim.x + threadIdx.x; i < total; i += gridDim.x * blockDim.x) {
    int lane = i & 63;
    int block = i >> 6;
    int kc = block % kc_n;
    int nt = block / kc_n;
    int n = nt * 16 + (lane & 15);
    int k = kc * 32 + (lane >> 4) * 8;
    const float* s = sg.s + (size_t)n * sg.K + k;
    float4 v0 = *(const float4*)(s);
    float4 v1 = *(const float4*)(s + 4);
    u16x4 o0, o1;
    o0.x = f2bf(v0.x); o0.y = f2bf(v0.y); o0.z = f2bf(v0.z); o0.w = f2bf(v0.w);
    o1.x = f2bf(v1.x); o1.y = f2bf(v1.y); o1.z = f2bf(v1.z); o1.w = f2bf(v1.w);
    unsigned short* dp = sg.d + (size_t)i * 8;
    *(u16x4*)(dp) = o0;
    *(u16x4*)(dp + 4) = o1;
  }
}

struct GruP {
  const unsigned short* xbf;
  const unsigned short* wx[2][3];
  const unsigned short* wh[2][3];
  const float* bx[2][3];
  unsigned short* h0b[2];
  unsigned short* h1b;
  unsigned short* rh[2];
  unsigned short* y1;
  float* outh;
  unsigned* bar;
};

// two-level barrier, RELAXED-only atomics (no acquire->no buffer_inv, no release->no wbl2).
// producer ordering: explicit s_waitcnt vmcnt(0) before arrive (all h-stores are vmem).
// consumer ordering: data-dependent poll on LLC + signal fence; data reads are sc1 (bypass L2).
__device__ __forceinline__ void gbar(unsigned* bar, int p, int wg) {
  __syncthreads();
  if (threadIdx.x == 0) {
    unsigned* base = bar + (size_t)p * 256;
    unsigned* grp  = base + (wg >> 3) * 16;
    unsigned* root = base + 8 * 16;
    unsigned* flag = base + 9 * 16;
    asm volatile("s_waitcnt vmcnt(0)" ::: "memory");
    unsigned old = __hip_atomic_fetch_add(grp, 1u, __ATOMIC_RELAXED, __HIP_MEMORY_SCOPE_AGENT);
    if (old == 7u) {
      unsigned r = __hip_atomic_fetch_add(root, 1u, __ATOMIC_RELAXED, __HIP_MEMORY_SCOPE_AGENT);
      if (r == 7u)
        __hip_atomic_store(flag, 1u, __ATOMIC_RELAXED, __HIP_MEMORY_SCOPE_AGENT);
    }
    while (__hip_atomic_load(flag, __ATOMIC_RELAXED, __HIP_MEMORY_SCOPE_AGENT) == 0u)
      __builtin_amdgcn_s_sleep(1);
    __atomic_signal_fence(__ATOMIC_ACQ_REL);
  }
  __syncthreads();
}

template <int LAYER>
__device__ __forceinline__ void gru_body(const GruP& P, int wg) {
  const int c0 = (wg & 31) * 32;
  const int tid = threadIdx.x;
  const int w = tid >> 6;
  const int lane = tid & 63;
  const int lo = lane & 15;
  const int hi = lane >> 4;
  const int mw = w & 3;
  const int nw = w >> 2;
  constexpr int Kx = LAYER ? HD : IN;
  const int bA = 16 * mw + lo;
  const int koff = hi * 8;
  const int cC = c0 + nw * 16 + lo;
  const int nt = (c0 >> 4) + nw;

  const unsigned short* WXZ = P.wx[LAYER][0] + ((size_t)nt * (Kx >> 5)) * 512 + (size_t)lane * 8;
  const unsigned short* WXR = P.wx[LAYER][1] + ((size_t)nt * (Kx >> 5)) * 512 + (size_t)lane * 8;
  const unsigned short* WXG = P.wx[LAYER][2] + ((size_t)nt * (Kx >> 5)) * 512 + (size_t)lane * 8;
  const unsigned short* WHZ = P.wh[LAYER][0] + ((size_t)nt * (HD >> 5)) * 512 + (size_t)lane * 8;
  const unsigned short* WHR = P.wh[LAYER][1] + ((size_t)nt * (HD >> 5)) * 512 + (size_t)lane * 8;
  const unsigned short* WHG = P.wh[LAYER][2] + ((size_t)nt * (HD >> 5)) * 512 + (size_t)lane * 8;
  const float bz = P.bx[LAYER][0][cC];
  const float br = P.bx[LAYER][1][cC];
  const float bg = P.bx[LAYER][2][cC];
  unsigned short* RH = P.rh[LAYER];
  const int b0 = 16 * mw + 4 * hi;

  f32x4 hreg = {0.f, 0.f, 0.f, 0.f};
  f32x4 zreg = {0.f, 0.f, 0.f, 0.f};

  for (int p = 0; p <= SEQ; ++p) {
    const int t = LAYER ? (p - 1) : p;
    const bool act = LAYER ? (p >= 1) : (p < SEQ);

    // ---------------- phase A: z, r ----------------
    if (act) {
      const unsigned short* aX = (LAYER ? P.h0b[t & 1] + (size_t)bA * HD
                                        : P.xbf + ((size_t)bA * SEQ + t) * IN) + koff;
      const unsigned short* aH = (LAYER ? P.h1b : P.h0b[(t + 1) & 1]) + (size_t)bA * HD + koff;
      f32x4 az = {0.f,0.f,0.f,0.f}, ar = {0.f,0.f,0.f,0.f};
      #pragma unroll 8
      for (int kb = 0; kb < (Kx >> 5); ++kb) {
        bf16x8 a = LAYER ? ld_sc(aX + kb * 32) : *(const bf16x8*)(aX + kb * 32);
        az = mfma16(a, *(const bf16x8*)(WXZ + kb * 512), az);
        ar = mfma16(a, *(const bf16x8*)(WXR + kb * 512), ar);
      }
      #pragma unroll 8
      for (int kb = 0; kb < (HD >> 5); ++kb) {
        bf16x8 a = ld_sc(aH + kb * 32);
        az = mfma16(a, *(const bf16x8*)(WHZ + kb * 512), az);
        ar = mfma16(a, *(const bf16x8*)(WHR + kb * 512), ar);
      }
      #pragma unroll
      for (int q = 0; q < 4; ++q) {
        float z = sigmoidf_(az[q] + bz);
        float r = sigmoidf_(ar[q] + br);
        zreg[q] = z;
        st_sc16(&RH[(size_t)(b0 + q) * HD + cC], f2bf(r * hreg[q]));
      }
    }
    gbar(P.bar, 2 * p, wg);

    // ---------------- phase B: g, h-update ----------------
    if (act) {
      const unsigned short* aX = (LAYER ? P.h0b[t & 1] + (size_t)bA * HD
                                        : P.xbf + ((size_t)bA * SEQ + t) * IN) + koff;
      const unsigned short* aR = RH + (size_t)bA * HD + koff;
      f32x4 ag = {0.f,0.f,0.f,0.f};
      #pragma unroll 8
      for (int kb = 0; kb < (Kx >> 5); ++kb) {
        bf16x8 a = LAYER ? ld_sc(aX + kb * 32) : *(const bf16x8*)(aX + kb * 32);
        ag = mfma16(a, *(const bf16x8*)(WXG + kb * 512), ag);
      }
      #pragma unroll 8
      for (int kb = 0; kb < (HD >> 5); ++kb)
        ag = mfma16(ld_sc(aR + kb * 32), *(const bf16x8*)(WHG + kb * 512), ag);
      unsigned short* hb = LAYER ? P.h1b : P.h0b[t & 1];
      #pragma unroll
      for (int q = 0; q < 4; ++q) {
        float g = tanhf(ag[q] + bg);
        float hn = zreg[q] * hreg[q] + (1.f - zreg[q]) * g;
        hreg[q] = hn;
        unsigned short hv = f2bf(hn);
        st_sc16(&hb[(size_t)(b0 + q) * HD + cC], hv);
        if (LAYER) P.y1[(((size_t)(b0 + q)) * SEQ + t) * HD + cC] = hv;
      }
      if (t == SEQ - 1) {
        #pragma unroll
        for (int q = 0; q < 4; ++q)
          P.outh[(size_t)(b0 + q) * (2 * HD) + LAYER * HD + cC] = hreg[q];
      }
    }
    gbar(P.bar, 2 * p + 1, wg);
  }
}

__global__ __launch_bounds__(WGTH) void gru_persist(GruP P) {
  const int wg = blockIdx.x;
  if (wg < 32) gru_body<0>(P, wg);
  else gru_body<1>(P, wg);
}

// C[M=B*SEQ][ODIM] = Y[M][HD] @ Wp(packed)[ODIM][HD]^T + bias
__global__ __launch_bounds__(256) void out_gemm(const unsigned short* __restrict__ Y,
                                                const unsigned short* __restrict__ Wp,
                                                const float* __restrict__ bias,
                                                float* __restrict__ C) {
  const int w = threadIdx.x >> 6, lane = threadIdx.x & 63;
  const int lo = lane & 15, hi = lane >> 4;
  const int row0 = blockIdx.x * 64;
  const int col0 = blockIdx.y * 64 + w * 16;
  const unsigned short* wp = Wp + ((size_t)(col0 >> 4) * (HD >> 5)) * 512 + (size_t)lane * 8;
  const unsigned short* yp = Y + (size_t)(row0 + lo) * HD + hi * 8;
  f32x4 a0 = {0.f,0.f,0.f,0.f}, a1 = {0.f,0.f,0.f,0.f};
  f32x4 a2 = {0.f,0.f,0.f,0.f}, a3 = {0.f,0.f,0.f,0.f};
  #pragma unroll 4
  for (int kb = 0; kb < (HD >> 5); ++kb) {
    bf16x8 bw = *(const bf16x8*)(wp + kb * 512);
    const int k = kb * 32;
    a0 = mfma16(*(const bf16x8*)(yp + k), bw, a0);
    a1 = mfma16(*(const bf16x8*)(yp + (size_t)16 * HD + k), bw, a1);
    a2 = mfma16(*(const bf16x8*)(yp + (size_t)32 * HD + k), bw, a2);
    a3 = mfma16(*(const bf16x8*)(yp + (size_t)48 * HD + k), bw, a3);
  }
  const int cc = col0 + lo;
  const float bb = bias[cc];
  const int rbase = row0 + 4 * hi;
  #pragma unroll
  for (int q = 0; q < 4; ++q) {
    C[(size_t)(rbase + q) * ODIM + cc]      = a0[q] + bb;
    C[(size_t)(rbase + 16 + q) * ODIM + cc] = a1[q] + bb;
    C[(size_t)(rbase + 32 + q) * ODIM + cc] = a2[q] + bb;
    C[(size_t)(rbase + 48 + q) * ODIM + cc] = a3[q] + bb;
  }
}

extern "C" void kernel_launch(void* const* d_in, const int* in_sizes, int n_in,
                              void* d_out, int out_size, void* d_ws, size_t ws_size,
                              hipStream_t stream) {
  char* ws = (char*)d_ws;
  size_t off = 0;
  auto take = [&](size_t bytes) -> char* {
    char* p = ws + off;
    off += (bytes + 255) & ~(size_t)255;
    return p;
  };

  unsigned short* xbf = (unsigned short*)take((size_t)B * SEQ * IN * 2);
  unsigned short *wx0[3], *wh0[3], *wx1[3], *wh1[3];
  for (int g = 0; g < 3; ++g) wx0[g] = (unsigned short*)take((size_t)HD * IN * 2);
  for (int g = 0; g < 3; ++g) wh0[g] = (unsigned short*)take((size_t)HD * HD * 2);
  for (int g = 0; g < 3; ++g) wx1[g] = (unsigned short*)take((size_t)HD * HD * 2);
  for (int g = 0; g < 3; ++g) wh1[g] = (unsigned short*)take((size_t)HD * HD * 2);
  unsigned short* whyb = (unsigned short*)take((size_t)ODIM * HD * 2);
  unsigned short* y1 = (unsigned short*)take((size_t)B * SEQ * HD * 2);
  char* state0 = ws + off;
  unsigned short* h0b0 = (unsigned short*)take((size_t)B * HD * 2);
  unsigned short* h0b1 = (unsigned short*)take((size_t)B * HD * 2);
  unsigned short* h1b  = (unsigned short*)take((size_t)B * HD * 2);
  unsigned short* rh0 = (unsigned short*)take((size_t)B * HD * 2);
  unsigned short* rh1 = (unsigned short*)take((size_t)B * HD * 2);
  unsigned* bar = (unsigned*)take((size_t)514 * 256 * 4);
  size_t stateBytes = (size_t)((ws + off) - state0);

  {
    int n = B * SEQ * IN;
    hipLaunchKernelGGL(f32_to_bf16_k, dim3((n / 4 + 255) / 256), dim3(256), 0, stream,
                       (const float*)d_in[0], xbf, n);
  }

  {
    PackP pp;
    int s = 0;
    pp.seg[s++] = { (const float*)d_in[1],  wx0[0], HD, IN };
    pp.seg[s++] = { (const float*)d_in[4],  wx0[1], HD, IN };
    pp.seg[s++] = { (const float*)d_in[7],  wx0[2], HD, IN };
    pp.seg[s++] = { (const float*)d_in[3],  wh0[0], HD, HD };
    pp.seg[s++] = { (const float*)d_in[6],  wh0[1], HD, HD };
    pp.seg[s++] = { (const float*)d_in[9],  wh0[2], HD, HD };
    pp.seg[s++] = { (const float*)d_in[10], wx1[0], HD, HD };
    pp.seg[s++] = { (const float*)d_in[13], wx1[1], HD, HD };
    pp.seg[s++] = { (const float*)d_in[16], wx1[2], HD, HD };
    pp.seg[s++] = { (const float*)d_in[12], wh1[0], HD, HD };
    pp.seg[s++] = { (const float*)d_in[15], wh1[1], HD, HD };
    pp.seg[s++] = { (const float*)d_in[18], wh1[2], HD, HD };
    pp.seg[s++] = { (const float*)d_in[19], whyb, ODIM, HD };
    hipLaunchKernelGGL(pack_w, dim3(512, 13), dim3(256), 0, stream, pp);
  }

  hipMemsetAsync(state0, 0, stateBytes, stream);

  GruP P;
  P.xbf = xbf;
  for (int g = 0; g < 3; ++g) {
    P.wx[0][g] = wx0[g]; P.wh[0][g] = wh0[g];
    P.wx[1][g] = wx1[g]; P.wh[1][g] = wh1[g];
  }
  P.bx[0][0] = (const float*)d_in[2];  P.bx[0][1] = (const float*)d_in[5];  P.bx[0][2] = (const float*)d_in[8];
  P.bx[1][0] = (const float*)d_in[11]; P.bx[1][1] = (const float*)d_in[14]; P.bx[1][2] = (const float*)d_in[17];
  P.h0b[0] = h0b0; P.h0b[1] = h0b1; P.h1b = h1b;
  P.rh[0] = rh0; P.rh[1] = rh1;
  P.y1 = y1;
  P.outh = (float*)d_out + (size_t)B * SEQ * ODIM;
  P.bar = bar;

  hipLaunchKernelGGL(gru_persist, dim3(NWG), dim3(WGTH), 0, stream, P);

  hipLaunchKernelGGL(out_gemm, dim3((B * SEQ) / 64, ODIM / 64), dim3(256), 0, stream,
                     (const unsigned short*)y1, (const unsigned short*)whyb,
                     (const float*)d_in[20], (float*)d_out);
}

// Round 4
// 12849.261 us; speedup vs baseline: 1.6800x; 1.6800x over previous
//
#include <hip/hip_runtime.h>
#include <hip/hip_bf16.h>

#define B 64
#define SEQ 256
#define IN 512
#define HD 1024
#define ODIM 512

typedef __attribute__((ext_vector_type(8))) short bf16x8;
typedef __attribute__((ext_vector_type(4))) float f32x4;
typedef __attribute__((ext_vector_type(4))) unsigned short u16x4;

__device__ __forceinline__ f32x4 mfma16(bf16x8 a, bf16x8 b, f32x4 c) {
  return __builtin_amdgcn_mfma_f32_16x16x32_bf16(a, b, c, 0, 0, 0);
}

__device__ __forceinline__ unsigned short f2bf(float f) {
  unsigned u = __builtin_bit_cast(unsigned, f);
  u += 0x7FFFu + ((u >> 16) & 1u);
  return (unsigned short)(u >> 16);
}

__device__ __forceinline__ float sigmoidf_(float x) { return 1.f / (1.f + expf(-x)); }

// write-through (past L2, LLC-coherent) 2B store — proven cross-XCD in R3
__device__ __forceinline__ void stc2(unsigned short* p, unsigned short v) {
  unsigned vv = v;
  asm volatile("global_store_short %0, %1, off sc1" : : "v"(p), "v"(vv) : "memory");
}

// ---- x: f32 -> bf16 (row-major kept) ----
__global__ void f32_to_bf16_k(const float* __restrict__ s, unsigned short* __restrict__ d, int n) {
  int i = (blockIdx.x * blockDim.x + threadIdx.x) * 4;
  if (i < n) {
    float4 v = *reinterpret_cast<const float4*>(s + i);
    u16x4 o;
    o.x = f2bf(v.x); o.y = f2bf(v.y); o.z = f2bf(v.z); o.w = f2bf(v.w);
    *reinterpret_cast<u16x4*>(d + i) = o;
  }
}

// ---- weights: f32 [N][K] -> bf16 packed MFMA B-fragment layout ----
struct PackSeg { const float* s; unsigned short* d; int N; int K; };
struct PackP { PackSeg seg[13]; };

__global__ void pack_w(PackP P) {
  PackSeg sg = P.seg[blockIdx.y];
  const int kc_n = sg.K >> 5;
  const int total = (sg.N * sg.K) >> 3;
  for (int i = blockIdx.x * blockDim.x + threadIdx.x; i < total; i += gridDim.x * blockDim.x) {
    int lane = i & 63;
    int block = i >> 6;
    int kc = block % kc_n;
    int nt = block / kc_n;
    int n = nt * 16 + (lane & 15);
    int k = kc * 32 + (lane >> 4) * 8;
    const float* s = sg.s + (size_t)n * sg.K + k;
    float4 v0 = *(const float4*)(s);
    float4 v1 = *(const float4*)(s + 4);
    u16x4 o0, o1;
    o0.x = f2bf(v0.x); o0.y = f2bf(v0.y); o0.z = f2bf(v0.z); o0.w = f2bf(v0.w);
    o1.x = f2bf(v1.x); o1.y = f2bf(v1.y); o1.z = f2bf(v1.z); o1.w = f2bf(v1.w);
    unsigned short* dp = sg.d + (size_t)i * 8;
    *(u16x4*)(dp) = o0;
    *(u16x4*)(dp + 4) = o1;
  }
}

struct GruP {
  const unsigned short* xbf;
  const unsigned short* wx[2][3];
  const unsigned short* wh[2][3];
  const float* bx[2][3];
  unsigned short* h0b[2];
  unsigned short* h1b;
  unsigned short* rh[2];
  unsigned short* y1;
  float* outh;
  unsigned* bar;
};

// two-level monotonic barrier on 2 hot ping-pong line sets, relaxed atomics only.
// producer ordering: wave0's sc1 stores drained by vmcnt(0) (tid0 is wave0).
// consumer freshness: acquire fence (buffer_inv) after the barrier — weights are
// in VGPRs, so the L2 invalidate only touches the small h/x streams.
__device__ __forceinline__ void gbar(unsigned* bar, int idx, int wg) {
  __syncthreads();
  if (threadIdx.x == 0) {
    unsigned* base = bar + (size_t)(idx & 1) * 1024;
    unsigned* grp  = base + (wg >> 3) * 32;
    unsigned* root = base + 16 * 32;
    asm volatile("s_waitcnt vmcnt(0)" ::: "memory");
    unsigned old = __hip_atomic_fetch_add(grp, 1u, __ATOMIC_RELAXED, __HIP_MEMORY_SCOPE_AGENT);
    if ((old & 7u) == 7u)
      __hip_atomic_fetch_add(root, 1u, __ATOMIC_RELAXED, __HIP_MEMORY_SCOPE_AGENT);
    const unsigned target = 16u * (unsigned)((idx >> 1) + 1);
    while (__hip_atomic_load(root, __ATOMIC_RELAXED, __HIP_MEMORY_SCOPE_AGENT) < target)
      __builtin_amdgcn_s_sleep(1);
  }
  __syncthreads();
  __builtin_amdgcn_fence(__ATOMIC_ACQUIRE, "agent");
}

template <int LAYER>
__device__ void gru_body(const GruP& P, f32x4 (*red)[7][64]) {
  const int wgl = LAYER ? ((int)blockIdx.x - 64) : (int)blockIdx.x;
  const int tid = threadIdx.x;
  const int w = tid >> 6;             // 8 waves: K-slice owner
  const int lane = tid & 63;
  const int lo = lane & 15, hi = lane >> 4;
  const int cC = wgl * 16 + lo;       // output column
  constexpr int KX = LAYER ? HD : IN;
  constexpr int CX = KX / 256;        // Wx chunks per wave (L0:2, L1:4)
  constexpr int CH = 4;               // Wh chunks per wave (1024/8/32)
  const int kofh = w * 128 + hi * 8;
  const int kofx = w * (KX >> 3) + hi * 8;

  // ---- register-resident weights (loaded once) ----
  bf16x8 whz[CH], whr[CH], whg[CH];
  bf16x8 wxz[CX], wxr[CX], wxg[CX];
  #pragma unroll
  for (int c = 0; c < CH; ++c) {
    size_t o = ((size_t)wgl * (HD / 32) + w * CH + c) * 512 + (size_t)lane * 8;
    whz[c] = *(const bf16x8*)(P.wh[LAYER][0] + o);
    whr[c] = *(const bf16x8*)(P.wh[LAYER][1] + o);
    whg[c] = *(const bf16x8*)(P.wh[LAYER][2] + o);
  }
  #pragma unroll
  for (int c = 0; c < CX; ++c) {
    size_t o = ((size_t)wgl * (KX / 32) + w * CX + c) * 512 + (size_t)lane * 8;
    wxz[c] = *(const bf16x8*)(P.wx[LAYER][0] + o);
    wxr[c] = *(const bf16x8*)(P.wx[LAYER][1] + o);
    wxg[c] = *(const bf16x8*)(P.wx[LAYER][2] + o);
  }
  const float bz = P.bx[LAYER][0][cC];
  const float br = P.bx[LAYER][1][cC];
  const float bg = P.bx[LAYER][2][cC];
  unsigned short* RH = P.rh[LAYER];

  f32x4 hreg[4] = {{0,0,0,0},{0,0,0,0},{0,0,0,0},{0,0,0,0}};
  f32x4 zreg[4] = {{0,0,0,0},{0,0,0,0},{0,0,0,0},{0,0,0,0}};

  for (int p = 0; p <= SEQ; ++p) {
    const int t = LAYER ? (p - 1) : p;
    const bool act = LAYER ? (p >= 1) : (p < SEQ);
    f32x4 a0[4], a1[4];

    // ================= phase A: z, r partials =================
    if (act) {
      const unsigned short* hB = (LAYER ? P.h1b : P.h0b[(t + 1) & 1]) + kofh;
      const unsigned short* xB = LAYER ? P.h0b[t & 1] + kofh
                                       : P.xbf + (size_t)t * IN + kofx;
      const size_t xs = LAYER ? (size_t)HD : (size_t)SEQ * IN;
      #pragma unroll
      for (int mt = 0; mt < 4; ++mt) {
        const int row = 16 * mt + lo;
        bf16x8 ah[CH], ax[CX];
        #pragma unroll
        for (int c = 0; c < CH; ++c) ah[c] = *(const bf16x8*)(hB + (size_t)row * HD + c * 32);
        #pragma unroll
        for (int c = 0; c < CX; ++c) ax[c] = *(const bf16x8*)(xB + (size_t)row * xs + c * 32);
        f32x4 vz = {0,0,0,0}, vr = {0,0,0,0};
        #pragma unroll
        for (int c = 0; c < CH; ++c) { vz = mfma16(ah[c], whz[c], vz); vr = mfma16(ah[c], whr[c], vr); }
        #pragma unroll
        for (int c = 0; c < CX; ++c) { vz = mfma16(ax[c], wxz[c], vz); vr = mfma16(ax[c], wxr[c], vr); }
        a0[mt] = vz; a1[mt] = vr;
      }
    }
    __syncthreads();
    if (act && w) {
      #pragma unroll
      for (int mt = 0; mt < 4; ++mt) { red[mt][w - 1][lane] = a0[mt]; red[4 + mt][w - 1][lane] = a1[mt]; }
    }
    __syncthreads();
    if (act && w == 0) {
      #pragma unroll
      for (int mt = 0; mt < 4; ++mt) {
        f32x4 vz = a0[mt], vr = a1[mt];
        #pragma unroll
        for (int j = 0; j < 7; ++j) { vz += red[mt][j][lane]; vr += red[4 + mt][j][lane]; }
        #pragma unroll
        for (int q = 0; q < 4; ++q) {
          float z = sigmoidf_(vz[q] + bz);
          float r = sigmoidf_(vr[q] + br);
          zreg[mt][q] = z;
          stc2(RH + (size_t)(16 * mt + 4 * hi + q) * HD + cC, f2bf(r * hreg[mt][q]));
        }
      }
    }
    gbar(P.bar, 2 * p, blockIdx.x);

    // ================= phase B: g, h-update =================
    if (act) {
      const unsigned short* rB = RH + kofh;
      const unsigned short* xB = LAYER ? P.h0b[t & 1] + kofh
                                       : P.xbf + (size_t)t * IN + kofx;
      const size_t xs = LAYER ? (size_t)HD : (size_t)SEQ * IN;
      #pragma unroll
      for (int mt = 0; mt < 4; ++mt) {
        const int row = 16 * mt + lo;
        bf16x8 ah[CH], ax[CX];
        #pragma unroll
        for (int c = 0; c < CH; ++c) ah[c] = *(const bf16x8*)(rB + (size_t)row * HD + c * 32);
        #pragma unroll
        for (int c = 0; c < CX; ++c) ax[c] = *(const bf16x8*)(xB + (size_t)row * xs + c * 32);
        f32x4 vg = {0,0,0,0};
        #pragma unroll
        for (int c = 0; c < CH; ++c) vg = mfma16(ah[c], whg[c], vg);
        #pragma unroll
        for (int c = 0; c < CX; ++c) vg = mfma16(ax[c], wxg[c], vg);
        a0[mt] = vg;
      }
    }
    __syncthreads();
    if (act && w) {
      #pragma unroll
      for (int mt = 0; mt < 4; ++mt) red[mt][w - 1][lane] = a0[mt];
    }
    __syncthreads();
    if (act && w == 0) {
      unsigned short* hS = LAYER ? P.h1b : P.h0b[t & 1];
      #pragma unroll
      for (int mt = 0; mt < 4; ++mt) {
        f32x4 vg = a0[mt];
        #pragma unroll
        for (int j = 0; j < 7; ++j) vg += red[mt][j][lane];
        #pragma unroll
        for (int q = 0; q < 4; ++q) {
          const int row = 16 * mt + 4 * hi + q;
          float g = tanhf(vg[q] + bg);
          float hn = zreg[mt][q] * hreg[mt][q] + (1.f - zreg[mt][q]) * g;
          hreg[mt][q] = hn;
          unsigned short hv = f2bf(hn);
          stc2(hS + (size_t)row * HD + cC, hv);
          if (LAYER) P.y1[((size_t)row * SEQ + t) * HD + cC] = hv;
          if (t == SEQ - 1) P.outh[(size_t)row * (2 * HD) + LAYER * HD + cC] = hn;
        }
      }
    }
    gbar(P.bar, 2 * p + 1, blockIdx.x);
  }
}

__global__ __launch_bounds__(512, 2) void gru_persist(GruP P) {
  __shared__ f32x4 red[8][7][64];
  if (blockIdx.x < 64) gru_body<0>(P, red);
  else gru_body<1>(P, red);
}

// C[M=B*SEQ][ODIM] = Y[M][HD] @ Wp(packed)[ODIM][HD]^T + bias
__global__ __launch_bounds__(256) void out_gemm(const unsigned short* __restrict__ Y,
                                                const unsigned short* __restrict__ Wp,
                                                const float* __restrict__ bias,
                                                float* __restrict__ C) {
  const int w = threadIdx.x >> 6, lane = threadIdx.x & 63;
  const int lo = lane & 15, hi = lane >> 4;
  const int row0 = blockIdx.x * 64;
  const int col0 = blockIdx.y * 64 + w * 16;
  const unsigned short* wp = Wp + ((size_t)(col0 >> 4) * (HD >> 5)) * 512 + (size_t)lane * 8;
  const unsigned short* yp = Y + (size_t)(row0 + lo) * HD + hi * 8;
  f32x4 a0 = {0,0,0,0}, a1 = {0,0,0,0}, a2 = {0,0,0,0}, a3 = {0,0,0,0};
  #pragma unroll 4
  for (int kb = 0; kb < (HD >> 5); ++kb) {
    bf16x8 bw = *(const bf16x8*)(wp + kb * 512);
    const int k = kb * 32;
    a0 = mfma16(*(const bf16x8*)(yp + k), bw, a0);
    a1 = mfma16(*(const bf16x8*)(yp + (size_t)16 * HD + k), bw, a1);
    a2 = mfma16(*(const bf16x8*)(yp + (size_t)32 * HD + k), bw, a2);
    a3 = mfma16(*(const bf16x8*)(yp + (size_t)48 * HD + k), bw, a3);
  }
  const int cc = col0 + lo;
  const float bb = bias[cc];
  const int rbase = row0 + 4 * hi;
  #pragma unroll
  for (int q = 0; q < 4; ++q) {
    C[(size_t)(rbase + q) * ODIM + cc]      = a0[q] + bb;
    C[(size_t)(rbase + 16 + q) * ODIM + cc] = a1[q] + bb;
    C[(size_t)(rbase + 32 + q) * ODIM + cc] = a2[q] + bb;
    C[(size_t)(rbase + 48 + q) * ODIM + cc] = a3[q] + bb;
  }
}

extern "C" void kernel_launch(void* const* d_in, const int* in_sizes, int n_in,
                              void* d_out, int out_size, void* d_ws, size_t ws_size,
                              hipStream_t stream) {
  char* ws = (char*)d_ws;
  size_t off = 0;
  auto take = [&](size_t bytes) -> char* {
    char* p = ws + off;
    off += (bytes + 255) & ~(size_t)255;
    return p;
  };

  unsigned short* xbf = (unsigned short*)take((size_t)B * SEQ * IN * 2);
  unsigned short *wx0[3], *wh0[3], *wx1[3], *wh1[3];
  for (int g = 0; g < 3; ++g) wx0[g] = (unsigned short*)take((size_t)HD * IN * 2);
  for (int g = 0; g < 3; ++g) wh0[g] = (unsigned short*)take((size_t)HD * HD * 2);
  for (int g = 0; g < 3; ++g) wx1[g] = (unsigned short*)take((size_t)HD * HD * 2);
  for (int g = 0; g < 3; ++g) wh1[g] = (unsigned short*)take((size_t)HD * HD * 2);
  unsigned short* whyb = (unsigned short*)take((size_t)ODIM * HD * 2);
  unsigned short* y1 = (unsigned short*)take((size_t)B * SEQ * HD * 2);
  char* state0 = ws + off;
  unsigned short* h0b0 = (unsigned short*)take((size_t)B * HD * 2);
  unsigned short* h0b1 = (unsigned short*)take((size_t)B * HD * 2);
  unsigned short* h1b  = (unsigned short*)take((size_t)B * HD * 2);
  unsigned short* rh0 = (unsigned short*)take((size_t)B * HD * 2);
  unsigned short* rh1 = (unsigned short*)take((size_t)B * HD * 2);
  unsigned* bar = (unsigned*)take((size_t)2 * 1024 * 4);
  size_t stateBytes = (size_t)((ws + off) - state0);

  {
    int n = B * SEQ * IN;
    hipLaunchKernelGGL(f32_to_bf16_k, dim3((n / 4 + 255) / 256), dim3(256), 0, stream,
                       (const float*)d_in[0], xbf, n);
  }

  {
    PackP pp;
    int s = 0;
    pp.seg[s++] = { (const float*)d_in[1],  wx0[0], HD, IN };
    pp.seg[s++] = { (const float*)d_in[4],  wx0[1], HD, IN };
    pp.seg[s++] = { (const float*)d_in[7],  wx0[2], HD, IN };
    pp.seg[s++] = { (const float*)d_in[3],  wh0[0], HD, HD };
    pp.seg[s++] = { (const float*)d_in[6],  wh0[1], HD, HD };
    pp.seg[s++] = { (const float*)d_in[9],  wh0[2], HD, HD };
    pp.seg[s++] = { (const float*)d_in[10], wx1[0], HD, HD };
    pp.seg[s++] = { (const float*)d_in[13], wx1[1], HD, HD };
    pp.seg[s++] = { (const float*)d_in[16], wx1[2], HD, HD };
    pp.seg[s++] = { (const float*)d_in[12], wh1[0], HD, HD };
    pp.seg[s++] = { (const float*)d_in[15], wh1[1], HD, HD };
    pp.seg[s++] = { (const float*)d_in[18], wh1[2], HD, HD };
    pp.seg[s++] = { (const float*)d_in[19], whyb, ODIM, HD };
    hipLaunchKernelGGL(pack_w, dim3(512, 13), dim3(256), 0, stream, pp);
  }

  hipMemsetAsync(state0, 0, stateBytes, stream);

  GruP P;
  P.xbf = xbf;
  for (int g = 0; g < 3; ++g) {
    P.wx[0][g] = wx0[g]; P.wh[0][g] = wh0[g];
    P.wx[1][g] = wx1[g]; P.wh[1][g] = wh1[g];
  }
  P.bx[0][0] = (const float*)d_in[2];  P.bx[0][1] = (const float*)d_in[5];  P.bx[0][2] = (const float*)d_in[8];
  P.bx[1][0] = (const float*)d_in[11]; P.bx[1][1] = (const float*)d_in[14]; P.bx[1][2] = (const float*)d_in[17];
  P.h0b[0] = h0b0; P.h0b[1] = h0b1; P.h1b = h1b;
  P.rh[0] = rh0; P.rh[1] = rh1;
  P.y1 = y1;
  P.outh = (float*)d_out + (size_t)B * SEQ * ODIM;
  P.bar = bar;

  hipLaunchKernelGGL(gru_persist, dim3(128), dim3(512), 0, stream, P);

  hipLaunchKernelGGL(out_gemm, dim3((B * SEQ) / 64, ODIM / 64), dim3(256), 0, stream,
                     (const unsigned short*)y1, (const unsigned short*)whyb,
                     (const float*)d_in[20], (float*)d_out);
}

// Round 5
// 8018.934 us; speedup vs baseline: 2.6919x; 1.6024x over previous
//
#include <hip/hip_runtime.h>
#include <hip/hip_bf16.h>

#define B 64
#define SEQ 256
#define IN 512
#define HD 1024
#define ODIM 512
#define WGTH 512

typedef __attribute__((ext_vector_type(8))) short bf16x8;
typedef __attribute__((ext_vector_type(4))) float f32x4;
typedef __attribute__((ext_vector_type(4))) unsigned short u16x4;

__device__ __forceinline__ f32x4 mfma16(bf16x8 a, bf16x8 b, f32x4 c) {
  return __builtin_amdgcn_mfma_f32_16x16x32_bf16(a, b, c, 0, 0, 0);
}

__device__ __forceinline__ unsigned short f2bf(float f) {
  unsigned u = __builtin_bit_cast(unsigned, f);
  u += 0x7FFFu + ((u >> 16) & 1u);
  return (unsigned short)(u >> 16);
}

__device__ __forceinline__ float sigmoidf_(float x) { return 1.f / (1.f + expf(-x)); }

// write-through (past L2, LLC-coherent) 2B store — proven cross-XCD in R3/R4
__device__ __forceinline__ void stc2(unsigned short* p, unsigned short v) {
  unsigned vv = v;
  asm volatile("global_store_short %0, %1, off sc1" : : "v"(p), "v"(vv) : "memory");
}

// ---- x: f32 -> bf16 ----
__global__ void f32_to_bf16_k(const float* __restrict__ s, unsigned short* __restrict__ d, int n) {
  int i = (blockIdx.x * blockDim.x + threadIdx.x) * 4;
  if (i < n) {
    float4 v = *reinterpret_cast<const float4*>(s + i);
    u16x4 o;
    o.x = f2bf(v.x); o.y = f2bf(v.y); o.z = f2bf(v.z); o.w = f2bf(v.w);
    *reinterpret_cast<u16x4*>(d + i) = o;
  }
}

// ---- weights: f32 [N][K] -> bf16 packed MFMA B-fragment layout ----
struct PackSeg { const float* s; unsigned short* d; int N; int K; };
struct PackP { PackSeg seg[13]; };

__global__ void pack_w(PackP P) {
  PackSeg sg = P.seg[blockIdx.y];
  const int kc_n = sg.K >> 5;
  const int total = (sg.N * sg.K) >> 3;
  for (int i = blockIdx.x * blockDim.x + threadIdx.x; i < total; i += gridDim.x * blockDim.x) {
    int lane = i & 63;
    int block = i >> 6;
    int kc = block % kc_n;
    int nt = block / kc_n;
    int n = nt * 16 + (lane & 15);
    int k = kc * 32 + (lane >> 4) * 8;
    const float* s = sg.s + (size_t)n * sg.K + k;
    float4 v0 = *(const float4*)(s);
    float4 v1 = *(const float4*)(s + 4);
    u16x4 o0, o1;
    o0.x = f2bf(v0.x); o0.y = f2bf(v0.y); o0.z = f2bf(v0.z); o0.w = f2bf(v0.w);
    o1.x = f2bf(v1.x); o1.y = f2bf(v1.y); o1.z = f2bf(v1.z); o1.w = f2bf(v1.w);
    unsigned short* dp = sg.d + (size_t)i * 8;
    *(u16x4*)(dp) = o0;
    *(u16x4*)(dp + 4) = o1;
  }
}

struct GruP {
  const unsigned short* xbf;
  const unsigned short* wx[2][3];
  const unsigned short* wh[2][3];
  const float* bx[2][3];
  unsigned short* h0b[4];   // layer0 h ring (depth 4)
  unsigned short* h1b;
  unsigned short* rh[2];
  unsigned short* y1;
  float* outh;
  unsigned* bar;            // 4 regions (layer,kind) of 256 uints; root at +128
};

__device__ __forceinline__ unsigned ld_cnt(const unsigned* p) {
  return __hip_atomic_load(p, __ATOMIC_RELAXED, __HIP_MEMORY_SCOPE_AGENT);
}

// arrive: all waves drain stores (syncthreads), tid0 bumps group; every 8th bumps root
__device__ __forceinline__ void arrive_(unsigned* base, int wgl) {
  __syncthreads();
  if (threadIdx.x == 0) {
    unsigned old = __hip_atomic_fetch_add(base + (wgl >> 3) * 16, 1u,
                                          __ATOMIC_RELAXED, __HIP_MEMORY_SCOPE_AGENT);
    if ((old & 7u) == 7u)
      __hip_atomic_fetch_add(base + 128, 1u, __ATOMIC_RELAXED, __HIP_MEMORY_SCOPE_AGENT);
  }
}

__device__ __forceinline__ void wait1_(unsigned* root, unsigned tgt) {
  if (threadIdx.x == 0) {
    while (ld_cnt(root) < tgt) __builtin_amdgcn_s_sleep(1);
  }
  __syncthreads();
  __builtin_amdgcn_fence(__ATOMIC_ACQUIRE, "agent");
}

__device__ __forceinline__ void wait2_(unsigned* r1, unsigned t1, unsigned* r2, unsigned t2) {
  if (threadIdx.x == 0) {
    while (ld_cnt(r1) < t1) __builtin_amdgcn_s_sleep(1);
    while (ld_cnt(r2) < t2) __builtin_amdgcn_s_sleep(1);
  }
  __syncthreads();
  __builtin_amdgcn_fence(__ATOMIC_ACQUIRE, "agent");
}

template <int LAYER>
__device__ void gru_body(const GruP& P, f32x4 (*red)[7][64]) {
  const int wgl = (int)blockIdx.x & 63;
  const int tid = threadIdx.x;
  const int w = tid >> 6;            // 8 waves: k-slice owner; waves 0-3 also own m-tile w
  const int lane = tid & 63;
  const int lo = lane & 15, hi = lane >> 4;
  const int cC = wgl * 16 + lo;      // output column
  constexpr int KX = LAYER ? HD : IN;
  constexpr int CX = KX / 256;       // Wx chunks per wave (L0:2, L1:4)
  constexpr int CH = 4;              // Wh chunks per wave
  const int kslH = w * 128 + hi * 8;
  const int kslX = w * (KX >> 3) + hi * 8;

  // register-resident weights (loaded once; packed frag layout, ntile = wgl)
  bf16x8 whz[CH], whr[CH], whg[CH], wxz[CX], wxr[CX], wxg[CX];
  #pragma unroll
  for (int c = 0; c < CH; ++c) {
    size_t o = ((size_t)wgl * (HD / 32) + w * CH + c) * 512 + (size_t)lane * 8;
    whz[c] = *(const bf16x8*)(P.wh[LAYER][0] + o);
    whr[c] = *(const bf16x8*)(P.wh[LAYER][1] + o);
    whg[c] = *(const bf16x8*)(P.wh[LAYER][2] + o);
  }
  #pragma unroll
  for (int c = 0; c < CX; ++c) {
    size_t o = ((size_t)wgl * (KX / 32) + w * CX + c) * 512 + (size_t)lane * 8;
    wxz[c] = *(const bf16x8*)(P.wx[LAYER][0] + o);
    wxr[c] = *(const bf16x8*)(P.wx[LAYER][1] + o);
    wxg[c] = *(const bf16x8*)(P.wx[LAYER][2] + o);
  }
  const float bz = P.bx[LAYER][0][cC];
  const float br = P.bx[LAYER][1][cC];
  const float bg = P.bx[LAYER][2][cC];
  unsigned short* RH = P.rh[LAYER];

  unsigned* barOA = P.bar + (LAYER * 2 + 0) * 256;
  unsigned* barOB = P.bar + (LAYER * 2 + 1) * 256;
  unsigned* rootOA = barOA + 128;
  unsigned* rootOB = barOB + 128;
  unsigned* rootXA = P.bar + ((1 - LAYER) * 2 + 0) * 256 + 128;
  unsigned* rootXB = P.bar + ((1 - LAYER) * 2 + 1) * 256 + 128;

  f32x4 hreg = {0.f, 0.f, 0.f, 0.f};  // valid in waves 0-3 (m-tile w)
  f32x4 zreg = {0.f, 0.f, 0.f, 0.f};

  for (int t = 0; t < SEQ; ++t) {
    f32x4 vz[4], vr[4];

    // ======== A_pre (L0 only): x-projections for z,r — off critical path ========
    if constexpr (!LAYER) {
      const unsigned short* xB = P.xbf + (size_t)t * IN + kslX;
      #pragma unroll
      for (int mt = 0; mt < 4; ++mt) {
        bf16x8 ax[CX];
        #pragma unroll
        for (int c = 0; c < CX; ++c)
          ax[c] = *(const bf16x8*)(xB + (size_t)(16 * mt + lo) * (SEQ * IN) + c * 32);
        f32x4 a = {0,0,0,0}, b = {0,0,0,0};
        #pragma unroll
        for (int c = 0; c < CX; ++c) { a = mfma16(ax[c], wxz[c], a); b = mfma16(ax[c], wxr[c], b); }
        vz[mt] = a; vr[mt] = b;
      }
    }

    // ======== wait A: own prev-B; L1 also waits L0's B of step t ========
    if constexpr (LAYER) wait2_(rootOB, 8u * (unsigned)t, rootXB, 8u * (unsigned)(t + 1));
    else                 wait1_(rootOB, 8u * (unsigned)t);

    // ======== A_post: h-recurrent z,r ========
    {
      const unsigned short* hB = (LAYER ? P.h1b : P.h0b[(t + 3) & 3]) + kslH;
      const unsigned short* yB = LAYER ? P.h0b[t & 3] + kslX : nullptr;
      #pragma unroll
      for (int mt = 0; mt < 4; ++mt) {
        bf16x8 ah[CH];
        #pragma unroll
        for (int c = 0; c < CH; ++c)
          ah[c] = *(const bf16x8*)(hB + (size_t)(16 * mt + lo) * HD + c * 32);
        f32x4 a, b;
        if constexpr (LAYER) {
          bf16x8 ax[CX];
          #pragma unroll
          for (int c = 0; c < CX; ++c)
            ax[c] = *(const bf16x8*)(yB + (size_t)(16 * mt + lo) * HD + c * 32);
          a = {0,0,0,0}; b = {0,0,0,0};
          #pragma unroll
          for (int c = 0; c < CX; ++c) { a = mfma16(ax[c], wxz[c], a); b = mfma16(ax[c], wxr[c], b); }
        } else { a = vz[mt]; b = vr[mt]; }
        #pragma unroll
        for (int c = 0; c < CH; ++c) { a = mfma16(ah[c], whz[c], a); b = mfma16(ah[c], whr[c], b); }
        vz[mt] = a; vr[mt] = b;
      }
    }
    // reduce (waves write all m-tiles except their own; keep own in named regs)
    f32x4 keepz, keepr;
    #pragma unroll
    for (int mt = 0; mt < 4; ++mt) {
      if (w == mt) { keepz = vz[mt]; keepr = vr[mt]; }
      else {
        int col = (w > mt) ? (w - 1) : w;
        red[mt][col][lane] = vz[mt];
        red[4 + mt][col][lane] = vr[mt];
      }
    }
    __syncthreads();
    if (w < 4) {
      f32x4 sz = keepz, sr = keepr;
      #pragma unroll
      for (int j = 0; j < 7; ++j) { sz += red[w][j][lane]; sr += red[4 + w][j][lane]; }
      #pragma unroll
      for (int q = 0; q < 4; ++q) {
        float z = sigmoidf_(sz[q] + bz);
        float r = sigmoidf_(sr[q] + br);
        zreg[q] = z;
        stc2(RH + (size_t)(16 * w + 4 * hi + q) * HD + cC, f2bf(r * hreg[q]));
      }
    }
    arrive_(barOA, wgl);

    // ======== B_pre: xg projections (operands re-read from warm L2) ========
    f32x4 vg[4];
    {
      const unsigned short* gB = LAYER ? P.h0b[t & 3] + kslX
                                       : P.xbf + (size_t)t * IN + kslX;
      const size_t gs = LAYER ? (size_t)HD : (size_t)(SEQ * IN);
      #pragma unroll
      for (int mt = 0; mt < 4; ++mt) {
        bf16x8 ax[CX];
        #pragma unroll
        for (int c = 0; c < CX; ++c)
          ax[c] = *(const bf16x8*)(gB + (size_t)(16 * mt + lo) * gs + c * 32);
        f32x4 a = {0,0,0,0};
        #pragma unroll
        for (int c = 0; c < CX; ++c) a = mfma16(ax[c], wxg[c], a);
        vg[mt] = a;
      }
    }

    // ======== wait B: own A; L0 also waits L1's A of step t-4 (ring WAR) ========
    if constexpr (!LAYER) {
      if (t >= 4) wait2_(rootOA, 8u * (unsigned)(t + 1), rootXA, 8u * (unsigned)(t - 3));
      else        wait1_(rootOA, 8u * (unsigned)(t + 1));
    } else {
      wait1_(rootOA, 8u * (unsigned)(t + 1));
    }

    // ======== B_post: (r.h) @ Whg + h update ========
    {
      const unsigned short* rB = RH + kslH;
      #pragma unroll
      for (int mt = 0; mt < 4; ++mt) {
        bf16x8 ah[CH];
        #pragma unroll
        for (int c = 0; c < CH; ++c)
          ah[c] = *(const bf16x8*)(rB + (size_t)(16 * mt + lo) * HD + c * 32);
        f32x4 a = vg[mt];
        #pragma unroll
        for (int c = 0; c < CH; ++c) a = mfma16(ah[c], whg[c], a);
        vg[mt] = a;
      }
    }
    f32x4 keepg;
    #pragma unroll
    for (int mt = 0; mt < 4; ++mt) {
      if (w == mt) keepg = vg[mt];
      else {
        int col = (w > mt) ? (w - 1) : w;
        red[mt][col][lane] = vg[mt];
      }
    }
    __syncthreads();
    if (w < 4) {
      f32x4 sg = keepg;
      #pragma unroll
      for (int j = 0; j < 7; ++j) sg += red[w][j][lane];
      unsigned short* hW = LAYER ? P.h1b : P.h0b[t & 3];
      #pragma unroll
      for (int q = 0; q < 4; ++q) {
        const int row = 16 * w + 4 * hi + q;
        float g = tanhf(sg[q] + bg);
        float hn = zreg[q] * hreg[q] + (1.f - zreg[q]) * g;
        hreg[q] = hn;
        unsigned short hv = f2bf(hn);
        stc2(hW + (size_t)row * HD + cC, hv);
        if (LAYER) P.y1[((size_t)row * SEQ + t) * HD + cC] = hv;
        if (t == SEQ - 1) P.outh[(size_t)row * (2 * HD) + LAYER * HD + cC] = hn;
      }
    }
    arrive_(barOB, wgl);
  }
}

__global__ __launch_bounds__(WGTH, 2) void gru_persist(GruP P) {
  __shared__ f32x4 red[8][7][64];
  if (blockIdx.x < 64) gru_body<0>(P, red);
  else gru_body<1>(P, red);
}

// C[M=B*SEQ][ODIM] = Y[M][HD] @ Wp(packed)[ODIM][HD]^T + bias
__global__ __launch_bounds__(256) void out_gemm(const unsigned short* __restrict__ Y,
                                                const unsigned short* __restrict__ Wp,
                                                const float* __restrict__ bias,
                                                float* __restrict__ C) {
  const int w = threadIdx.x >> 6, lane = threadIdx.x & 63;
  const int lo = lane & 15, hi = lane >> 4;
  const int row0 = blockIdx.x * 64;
  const int col0 = blockIdx.y * 64 + w * 16;
  const unsigned short* wp = Wp + ((size_t)(col0 >> 4) * (HD >> 5)) * 512 + (size_t)lane * 8;
  const unsigned short* yp = Y + (size_t)(row0 + lo) * HD + hi * 8;
  f32x4 a0 = {0,0,0,0}, a1 = {0,0,0,0}, a2 = {0,0,0,0}, a3 = {0,0,0,0};
  #pragma unroll 4
  for (int kb = 0; kb < (HD >> 5); ++kb) {
    bf16x8 bw = *(const bf16x8*)(wp + kb * 512);
    const int k = kb * 32;
    a0 = mfma16(*(const bf16x8*)(yp + k), bw, a0);
    a1 = mfma16(*(const bf16x8*)(yp + (size_t)16 * HD + k), bw, a1);
    a2 = mfma16(*(const bf16x8*)(yp + (size_t)32 * HD + k), bw, a2);
    a3 = mfma16(*(const bf16x8*)(yp + (size_t)48 * HD + k), bw, a3);
  }
  const int cc = col0 + lo;
  const float bb = bias[cc];
  const int rbase = row0 + 4 * hi;
  #pragma unroll
  for (int q = 0; q < 4; ++q) {
    C[(size_t)(rbase + q) * ODIM + cc]      = a0[q] + bb;
    C[(size_t)(rbase + 16 + q) * ODIM + cc] = a1[q] + bb;
    C[(size_t)(rbase + 32 + q) * ODIM + cc] = a2[q] + bb;
    C[(size_t)(rbase + 48 + q) * ODIM + cc] = a3[q] + bb;
  }
}

extern "C" void kernel_launch(void* const* d_in, const int* in_sizes, int n_in,
                              void* d_out, int out_size, void* d_ws, size_t ws_size,
                              hipStream_t stream) {
  char* ws = (char*)d_ws;
  size_t off = 0;
  auto take = [&](size_t bytes) -> char* {
    char* p = ws + off;
    off += (bytes + 255) & ~(size_t)255;
    return p;
  };

  unsigned short* xbf = (unsigned short*)take((size_t)B * SEQ * IN * 2);
  unsigned short *wx0[3], *wh0[3], *wx1[3], *wh1[3];
  for (int g = 0; g < 3; ++g) wx0[g] = (unsigned short*)take((size_t)HD * IN * 2);
  for (int g = 0; g < 3; ++g) wh0[g] = (unsigned short*)take((size_t)HD * HD * 2);
  for (int g = 0; g < 3; ++g) wx1[g] = (unsigned short*)take((size_t)HD * HD * 2);
  for (int g = 0; g < 3; ++g) wh1[g] = (unsigned short*)take((size_t)HD * HD * 2);
  unsigned short* whyb = (unsigned short*)take((size_t)ODIM * HD * 2);
  unsigned short* y1 = (unsigned short*)take((size_t)B * SEQ * HD * 2);
  char* state0 = ws + off;
  unsigned short* h0r[4];
  for (int i = 0; i < 4; ++i) h0r[i] = (unsigned short*)take((size_t)B * HD * 2);
  unsigned short* h1b = (unsigned short*)take((size_t)B * HD * 2);
  unsigned short* rh0 = (unsigned short*)take((size_t)B * HD * 2);
  unsigned short* rh1 = (unsigned short*)take((size_t)B * HD * 2);
  unsigned* bar = (unsigned*)take((size_t)8 * 1024);
  size_t stateBytes = (size_t)((ws + off) - state0);

  {
    int n = B * SEQ * IN;
    hipLaunchKernelGGL(f32_to_bf16_k, dim3((n / 4 + 255) / 256), dim3(256), 0, stream,
                       (const float*)d_in[0], xbf, n);
  }

  {
    PackP pp;
    int s = 0;
    pp.seg[s++] = { (const float*)d_in[1],  wx0[0], HD, IN };
    pp.seg[s++] = { (const float*)d_in[4],  wx0[1], HD, IN };
    pp.seg[s++] = { (const float*)d_in[7],  wx0[2], HD, IN };
    pp.seg[s++] = { (const float*)d_in[3],  wh0[0], HD, HD };
    pp.seg[s++] = { (const float*)d_in[6],  wh0[1], HD, HD };
    pp.seg[s++] = { (const float*)d_in[9],  wh0[2], HD, HD };
    pp.seg[s++] = { (const float*)d_in[10], wx1[0], HD, HD };
    pp.seg[s++] = { (const float*)d_in[13], wx1[1], HD, HD };
    pp.seg[s++] = { (const float*)d_in[16], wx1[2], HD, HD };
    pp.seg[s++] = { (const float*)d_in[12], wh1[0], HD, HD };
    pp.seg[s++] = { (const float*)d_in[15], wh1[1], HD, HD };
    pp.seg[s++] = { (const float*)d_in[18], wh1[2], HD, HD };
    pp.seg[s++] = { (const float*)d_in[19], whyb, ODIM, HD };
    hipLaunchKernelGGL(pack_w, dim3(512, 13), dim3(256), 0, stream, pp);
  }

  hipMemsetAsync(state0, 0, stateBytes, stream);

  GruP P;
  P.xbf = xbf;
  for (int g = 0; g < 3; ++g) {
    P.wx[0][g] = wx0[g]; P.wh[0][g] = wh0[g];
    P.wx[1][g] = wx1[g]; P.wh[1][g] = wh1[g];
  }
  P.bx[0][0] = (const float*)d_in[2];  P.bx[0][1] = (const float*)d_in[5];  P.bx[0][2] = (const float*)d_in[8];
  P.bx[1][0] = (const float*)d_in[11]; P.bx[1][1] = (const float*)d_in[14]; P.bx[1][2] = (const float*)d_in[17];
  for (int i = 0; i < 4; ++i) P.h0b[i] = h0r[i];
  P.h1b = h1b;
  P.rh[0] = rh0; P.rh[1] = rh1;
  P.y1 = y1;
  P.outh = (float*)d_out + (size_t)B * SEQ * ODIM;
  P.bar = bar;

  hipLaunchKernelGGL(gru_persist, dim3(128), dim3(WGTH), 0, stream, P);

  hipLaunchKernelGGL(out_gemm, dim3((B * SEQ) / 64, ODIM / 64), dim3(256), 0, stream,
                     (const unsigned short*)y1, (const unsigned short*)whyb,
                     (const float*)d_in[20], (float*)d_out);
}

// Round 6
// 6086.001 us; speedup vs baseline: 3.5469x; 1.3176x over previous
//
#include <hip/hip_runtime.h>
#include <hip/hip_bf16.h>

#define B 64
#define SEQ 256
#define IN 512
#define HD 1024
#define ODIM 512
#define WGTH 512

typedef __attribute__((ext_vector_type(8))) short bf16x8;
typedef __attribute__((ext_vector_type(4))) float f32x4;
typedef __attribute__((ext_vector_type(4))) unsigned short u16x4;

__device__ __forceinline__ f32x4 mfma16(bf16x8 a, bf16x8 b, f32x4 c) {
  return __builtin_amdgcn_mfma_f32_16x16x32_bf16(a, b, c, 0, 0, 0);
}

__device__ __forceinline__ unsigned short f2bf(float f) {
  unsigned u = __builtin_bit_cast(unsigned, f);
  u += 0x7FFFu + ((u >> 16) & 1u);
  return (unsigned short)(u >> 16);
}

__device__ __forceinline__ float sigmoidf_(float x) { return 1.f / (1.f + expf(-x)); }

// write-through (past L2, LLC-coherent) 2B store — proven cross-XCD R3-R5
__device__ __forceinline__ void stc2(unsigned short* p, unsigned short v) {
  unsigned vv = v;
  asm volatile("global_store_short %0, %1, off sc1" : : "v"(p), "v"(vv) : "memory");
}

// coherent 16B load: bypass L1+L2, read LLC. No waitcnt — caller manages vmcnt.
__device__ __forceinline__ void ldg16(bf16x8& d, const unsigned short* p) {
  asm volatile("global_load_dwordx4 %0, %1, off sc0 sc1" : "=v"(d) : "v"(p) : "memory");
}

template <int N>
__device__ __forceinline__ void vmwait() {
  asm volatile("s_waitcnt vmcnt(%0)" :: "i"(N) : "memory");
  __builtin_amdgcn_sched_barrier(0);
}

// ---------------- distributed-flag barrier (no RMW, no shared hot line) ----
// region = 64 flags, one 64B line per WG. value = steps completed (monotonic).
__device__ __forceinline__ void flag_set(unsigned* fl, int wgl, unsigned val) {
  if (threadIdx.x == 0) {
    unsigned* p = fl + wgl * 16;
    asm volatile("s_waitcnt vmcnt(0)\n\t"
                 "global_store_dword %0, %1, off sc0 sc1"
                 :: "v"(p), "v"(val) : "memory");
  }
}

__device__ __forceinline__ void flag_poll(const unsigned* fl, unsigned tgt) {
  if (threadIdx.x < 64) {
    const unsigned* p = fl + threadIdx.x * 16;
    for (;;) {
      unsigned v;
      asm volatile("global_load_dword %0, %1, off sc0 sc1\n\t"
                   "s_waitcnt vmcnt(0)" : "=v"(v) : "v"(p) : "memory");
      if (__ballot(v < tgt) == 0ull) break;
      __builtin_amdgcn_s_sleep(2);
    }
  }
  __syncthreads();
}

__device__ __forceinline__ void flag_poll2(const unsigned* f1, unsigned t1,
                                           const unsigned* f2, unsigned t2) {
  if (threadIdx.x < 64) {
    const unsigned* p1 = f1 + threadIdx.x * 16;
    const unsigned* p2 = f2 + threadIdx.x * 16;
    for (;;) {
      unsigned v1, v2;
      asm volatile("global_load_dword %0, %2, off sc0 sc1\n\t"
                   "global_load_dword %1, %3, off sc0 sc1\n\t"
                   "s_waitcnt vmcnt(0)"
                   : "=v"(v1), "=v"(v2) : "v"(p1), "v"(p2) : "memory");
      if ((__ballot(v1 < t1) | __ballot(v2 < t2)) == 0ull) break;
      __builtin_amdgcn_s_sleep(2);
    }
  }
  __syncthreads();
}

// ---- x: f32 -> bf16 ----
__global__ void f32_to_bf16_k(const float* __restrict__ s, unsigned short* __restrict__ d, int n) {
  int i = (blockIdx.x * blockDim.x + threadIdx.x) * 4;
  if (i < n) {
    float4 v = *reinterpret_cast<const float4*>(s + i);
    u16x4 o;
    o.x = f2bf(v.x); o.y = f2bf(v.y); o.z = f2bf(v.z); o.w = f2bf(v.w);
    *reinterpret_cast<u16x4*>(d + i) = o;
  }
}

// ---- weights: f32 [N][K] -> bf16 packed MFMA B-fragment layout ----
struct PackSeg { const float* s; unsigned short* d; int N; int K; };
struct PackP { PackSeg seg[13]; };

__global__ void pack_w(PackP P) {
  PackSeg sg = P.seg[blockIdx.y];
  const int kc_n = sg.K >> 5;
  const int total = (sg.N * sg.K) >> 3;
  for (int i = blockIdx.x * blockDim.x + threadIdx.x; i < total; i += gridDim.x * blockDim.x) {
    int lane = i & 63;
    int block = i >> 6;
    int kc = block % kc_n;
    int nt = block / kc_n;
    int n = nt * 16 + (lane & 15);
    int k = kc * 32 + (lane >> 4) * 8;
    const float* s = sg.s + (size_t)n * sg.K + k;
    float4 v0 = *(const float4*)(s);
    float4 v1 = *(const float4*)(s + 4);
    u16x4 o0, o1;
    o0.x = f2bf(v0.x); o0.y = f2bf(v0.y); o0.z = f2bf(v0.z); o0.w = f2bf(v0.w);
    o1.x = f2bf(v1.x); o1.y = f2bf(v1.y); o1.z = f2bf(v1.z); o1.w = f2bf(v1.w);
    unsigned short* dp = sg.d + (size_t)i * 8;
    *(u16x4*)(dp) = o0;
    *(u16x4*)(dp + 4) = o1;
  }
}

struct GruP {
  const unsigned short* xbf;
  const unsigned short* wx[2][3];
  const unsigned short* wh[2][3];
  const float* bx[2][3];
  unsigned short* h0b[4];   // layer0 h ring (depth 4)
  unsigned short* h1b;
  unsigned short* rh[2];
  unsigned short* y1;
  float* outh;
  unsigned* bar;            // 4 flag regions x 4KB (L0A,L0B,L1A,L1B)
};

// issue 4 sc-loads for m-tile `mt` into slot array
#define GISS(mt, sArr, baseP) do { \
    const unsigned short* _p = (baseP) + (size_t)(16 * (mt) + lo) * HD; \
    ldg16(sArr[0], _p);      ldg16(sArr[1], _p + 32); \
    ldg16(sArr[2], _p + 64); ldg16(sArr[3], _p + 96); \
  } while (0)

#define GCMP2(mt, sArr, wz_, wr_) do { \
    f32x4 _a = vz[mt], _b = vr[mt]; \
    _a = mfma16(sArr[0], wz_[0], _a); _b = mfma16(sArr[0], wr_[0], _b); \
    _a = mfma16(sArr[1], wz_[1], _a); _b = mfma16(sArr[1], wr_[1], _b); \
    _a = mfma16(sArr[2], wz_[2], _a); _b = mfma16(sArr[2], wr_[2], _b); \
    _a = mfma16(sArr[3], wz_[3], _a); _b = mfma16(sArr[3], wr_[3], _b); \
    vz[mt] = _a; vr[mt] = _b; \
  } while (0)

#define GCMP1(mt, sArr, wg_) do { \
    f32x4 _a = vg[mt]; \
    _a = mfma16(sArr[0], wg_[0], _a); _a = mfma16(sArr[1], wg_[1], _a); \
    _a = mfma16(sArr[2], wg_[2], _a); _a = mfma16(sArr[3], wg_[3], _a); \
    vg[mt] = _a; \
  } while (0)

template <int LAYER>
__device__ void gru_body(const GruP& P, f32x4 (*red)[7][64]) {
  const int wgl = (int)blockIdx.x & 63;
  const int tid = threadIdx.x;
  const int w = tid >> 6;            // 8 waves: k-slice owner; waves 0-3 own m-tile w
  const int lane = tid & 63;
  const int lo = lane & 15, hi = lane >> 4;
  const int cC = wgl * 16 + lo;
  constexpr int KX = LAYER ? HD : IN;
  constexpr int CX = KX / 256;       // L0:2, L1:4
  constexpr int CH = 4;
  const int kslH = w * 128 + hi * 8;
  const int kslX = w * (KX >> 3) + hi * 8;

  // register-resident weights (packed frag layout, ntile = wgl)
  bf16x8 whz[CH], whr[CH], whg[CH], wxz[CX], wxr[CX], wxg[CX];
  #pragma unroll
  for (int c = 0; c < CH; ++c) {
    size_t o = ((size_t)wgl * (HD / 32) + w * CH + c) * 512 + (size_t)lane * 8;
    whz[c] = *(const bf16x8*)(P.wh[LAYER][0] + o);
    whr[c] = *(const bf16x8*)(P.wh[LAYER][1] + o);
    whg[c] = *(const bf16x8*)(P.wh[LAYER][2] + o);
  }
  #pragma unroll
  for (int c = 0; c < CX; ++c) {
    size_t o = ((size_t)wgl * (KX / 32) + w * CX + c) * 512 + (size_t)lane * 8;
    wxz[c] = *(const bf16x8*)(P.wx[LAYER][0] + o);
    wxr[c] = *(const bf16x8*)(P.wx[LAYER][1] + o);
    wxg[c] = *(const bf16x8*)(P.wx[LAYER][2] + o);
  }
  const float bz = P.bx[LAYER][0][cC];
  const float br = P.bx[LAYER][1][cC];
  const float bg = P.bx[LAYER][2][cC];
  unsigned short* RH = P.rh[LAYER];

  unsigned* flAmy = P.bar + (LAYER * 2 + 0) * 1024;
  unsigned* flBmy = P.bar + (LAYER * 2 + 1) * 1024;
  unsigned* flBot = P.bar + ((1 - LAYER) * 2 + 1) * 1024;

  f32x4 hreg = {0.f, 0.f, 0.f, 0.f};
  f32x4 zreg = {0.f, 0.f, 0.f, 0.f};

  for (int t = 0; t < SEQ; ++t) {
    f32x4 vz[4], vr[4];
    bf16x8 sS0[4], sS1[4];

    // ===== A_pre (L0): x-projections z,r — before the wait =====
    if constexpr (!LAYER) {
      const unsigned short* xB = P.xbf + (size_t)t * IN + kslX;
      #pragma unroll
      for (int mt = 0; mt < 4; ++mt) {
        const unsigned short* xp = xB + (size_t)(16 * mt + lo) * (SEQ * IN);
        bf16x8 x0 = *(const bf16x8*)(xp);
        bf16x8 x1 = *(const bf16x8*)(xp + 32);
        f32x4 a = {0,0,0,0}, b = {0,0,0,0};
        a = mfma16(x0, wxz[0], a); a = mfma16(x1, wxz[1], a);
        b = mfma16(x0, wxr[0], b); b = mfma16(x1, wxr[1], b);
        vz[mt] = a; vr[mt] = b;
      }
      if (t) flag_poll(flBmy, (unsigned)t);             // own B(t-1)
    } else {
      flag_poll2(flBot, (unsigned)(t + 1), flBmy, (unsigned)t);  // L0-B(t) + own B(t-1)
    }

    // ===== A_post =====
    if constexpr (LAYER) {
      const unsigned short* yB = P.h0b[t & 3] + kslH;   // y0(t), stride HD
      #pragma unroll
      for (int mt = 0; mt < 4; ++mt) { vz[mt] = {0,0,0,0}; vr[mt] = {0,0,0,0}; }
      GISS(0, sS0, yB); GISS(1, sS1, yB);
      vmwait<4>(); GCMP2(0, sS0, wxz, wxr); GISS(2, sS0, yB);
      vmwait<4>(); GCMP2(1, sS1, wxz, wxr); GISS(3, sS1, yB);
      vmwait<4>(); GCMP2(2, sS0, wxz, wxr);
      vmwait<0>(); GCMP2(3, sS1, wxz, wxr);
    }
    {
      const unsigned short* hB = (LAYER ? P.h1b : P.h0b[(t + 3) & 3]) + kslH;
      GISS(0, sS0, hB); GISS(1, sS1, hB);
      vmwait<4>(); GCMP2(0, sS0, whz, whr); GISS(2, sS0, hB);
      vmwait<4>(); GCMP2(1, sS1, whz, whr); GISS(3, sS1, hB);
      vmwait<4>(); GCMP2(2, sS0, whz, whr);
      vmwait<0>(); GCMP2(3, sS1, whz, whr);
    }
    // reduce z,r
    f32x4 keepz, keepr;
    #pragma unroll
    for (int mt = 0; mt < 4; ++mt) {
      if (w == mt) { keepz = vz[mt]; keepr = vr[mt]; }
      else {
        int col = (w > mt) ? (w - 1) : w;
        red[mt][col][lane] = vz[mt];
        red[4 + mt][col][lane] = vr[mt];
      }
    }
    __syncthreads();
    if (w < 4) {
      f32x4 sz = keepz, sr = keepr;
      #pragma unroll
      for (int j = 0; j < 7; ++j) { sz += red[w][j][lane]; sr += red[4 + w][j][lane]; }
      #pragma unroll
      for (int q = 0; q < 4; ++q) {
        float z = sigmoidf_(sz[q] + bz);
        float r = sigmoidf_(sr[q] + br);
        zreg[q] = z;
        stc2(RH + (size_t)(16 * w + 4 * hi + q) * HD + cC, f2bf(r * hreg[q]));
      }
    }
    asm volatile("s_waitcnt vmcnt(0)" ::: "memory");
    __syncthreads();
    flag_set(flAmy, wgl, (unsigned)(t + 1));

    // ===== B_pre: xg projections — before the wait =====
    f32x4 vg[4];
    if constexpr (LAYER) {
      const unsigned short* yB = P.h0b[t & 3] + kslH;
      #pragma unroll
      for (int mt = 0; mt < 4; ++mt) vg[mt] = {0,0,0,0};
      GISS(0, sS0, yB); GISS(1, sS1, yB);
      vmwait<4>(); GCMP1(0, sS0, wxg); GISS(2, sS0, yB);
      vmwait<4>(); GCMP1(1, sS1, wxg); GISS(3, sS1, yB);
      vmwait<4>(); GCMP1(2, sS0, wxg);
      vmwait<0>(); GCMP1(3, sS1, wxg);
    } else {
      const unsigned short* xB = P.xbf + (size_t)t * IN + kslX;
      #pragma unroll
      for (int mt = 0; mt < 4; ++mt) {
        const unsigned short* xp = xB + (size_t)(16 * mt + lo) * (SEQ * IN);
        bf16x8 x0 = *(const bf16x8*)(xp);
        bf16x8 x1 = *(const bf16x8*)(xp + 32);
        f32x4 a = {0,0,0,0};
        a = mfma16(x0, wxg[0], a); a = mfma16(x1, wxg[1], a);
        vg[mt] = a;
      }
    }

    // ===== wait B: own A; L0 also waits L1-B(t-4) (ring WAR, race-fixed) =====
    if constexpr (!LAYER) {
      if (t >= 4) flag_poll2(flAmy, (unsigned)(t + 1), flBot, (unsigned)(t - 3));
      else        flag_poll(flAmy, (unsigned)(t + 1));
    } else {
      flag_poll(flAmy, (unsigned)(t + 1));
    }

    // ===== B_post: (r.h) @ Whg + h update =====
    {
      const unsigned short* rB = RH + kslH;
      GISS(0, sS0, rB); GISS(1, sS1, rB);
      vmwait<4>(); GCMP1(0, sS0, whg); GISS(2, sS0, rB);
      vmwait<4>(); GCMP1(1, sS1, whg); GISS(3, sS1, rB);
      vmwait<4>(); GCMP1(2, sS0, whg);
      vmwait<0>(); GCMP1(3, sS1, whg);
    }
    f32x4 keepg;
    #pragma unroll
    for (int mt = 0; mt < 4; ++mt) {
      if (w == mt) keepg = vg[mt];
      else { int col = (w > mt) ? (w - 1) : w; red[mt][col][lane] = vg[mt]; }
    }
    __syncthreads();
    if (w < 4) {
      f32x4 sg = keepg;
      #pragma unroll
      for (int j = 0; j < 7; ++j) sg += red[w][j][lane];
      unsigned short* hW = LAYER ? P.h1b : P.h0b[t & 3];
      #pragma unroll
      for (int q = 0; q < 4; ++q) {
        const int row = 16 * w + 4 * hi + q;
        float g = tanhf(sg[q] + bg);
        float hn = zreg[q] * hreg[q] + (1.f - zreg[q]) * g;
        hreg[q] = hn;
        unsigned short hv = f2bf(hn);
        stc2(hW + (size_t)row * HD + cC, hv);
        if (LAYER) P.y1[((size_t)row * SEQ + t) * HD + cC] = hv;
        if (t == SEQ - 1) P.outh[(size_t)row * (2 * HD) + LAYER * HD + cC] = hn;
      }
    }
    asm volatile("s_waitcnt vmcnt(0)" ::: "memory");
    __syncthreads();
    flag_set(flBmy, wgl, (unsigned)(t + 1));
  }
}

__global__ __launch_bounds__(WGTH, 2) void gru_persist(GruP P) {
  __shared__ f32x4 red[8][7][64];
  if (blockIdx.x < 64) gru_body<0>(P, red);
  else gru_body<1>(P, red);
}

// C[M=B*SEQ][ODIM] = Y[M][HD] @ Wp(packed)[ODIM][HD]^T + bias
__global__ __launch_bounds__(256) void out_gemm(const unsigned short* __restrict__ Y,
                                                const unsigned short* __restrict__ Wp,
                                                const float* __restrict__ bias,
                                                float* __restrict__ C) {
  const int w = threadIdx.x >> 6, lane = threadIdx.x & 63;
  const int lo = lane & 15, hi = lane >> 4;
  const int row0 = blockIdx.x * 64;
  const int col0 = blockIdx.y * 64 + w * 16;
  const unsigned short* wp = Wp + ((size_t)(col0 >> 4) * (HD >> 5)) * 512 + (size_t)lane * 8;
  const unsigned short* yp = Y + (size_t)(row0 + lo) * HD + hi * 8;
  f32x4 a0 = {0,0,0,0}, a1 = {0,0,0,0}, a2 = {0,0,0,0}, a3 = {0,0,0,0};
  #pragma unroll 4
  for (int kb = 0; kb < (HD >> 5); ++kb) {
    bf16x8 bw = *(const bf16x8*)(wp + kb * 512);
    const int k = kb * 32;
    a0 = mfma16(*(const bf16x8*)(yp + k), bw, a0);
    a1 = mfma16(*(const bf16x8*)(yp + (size_t)16 * HD + k), bw, a1);
    a2 = mfma16(*(const bf16x8*)(yp + (size_t)32 * HD + k), bw, a2);
    a3 = mfma16(*(const bf16x8*)(yp + (size_t)48 * HD + k), bw, a3);
  }
  const int cc = col0 + lo;
  const float bb = bias[cc];
  const int rbase = row0 + 4 * hi;
  #pragma unroll
  for (int q = 0; q < 4; ++q) {
    C[(size_t)(rbase + q) * ODIM + cc]      = a0[q] + bb;
    C[(size_t)(rbase + 16 + q) * ODIM + cc] = a1[q] + bb;
    C[(size_t)(rbase + 32 + q) * ODIM + cc] = a2[q] + bb;
    C[(size_t)(rbase + 48 + q) * ODIM + cc] = a3[q] + bb;
  }
}

extern "C" void kernel_launch(void* const* d_in, const int* in_sizes, int n_in,
                              void* d_out, int out_size, void* d_ws, size_t ws_size,
                              hipStream_t stream) {
  char* ws = (char*)d_ws;
  size_t off = 0;
  auto take = [&](size_t bytes) -> char* {
    char* p = ws + off;
    off += (bytes + 255) & ~(size_t)255;
    return p;
  };

  unsigned short* xbf = (unsigned short*)take((size_t)B * SEQ * IN * 2);
  unsigned short *wx0[3], *wh0[3], *wx1[3], *wh1[3];
  for (int g = 0; g < 3; ++g) wx0[g] = (unsigned short*)take((size_t)HD * IN * 2);
  for (int g = 0; g < 3; ++g) wh0[g] = (unsigned short*)take((size_t)HD * HD * 2);
  for (int g = 0; g < 3; ++g) wx1[g] = (unsigned short*)take((size_t)HD * HD * 2);
  for (int g = 0; g < 3; ++g) wh1[g] = (unsigned short*)take((size_t)HD * HD * 2);
  unsigned short* whyb = (unsigned short*)take((size_t)ODIM * HD * 2);
  unsigned short* y1 = (unsigned short*)take((size_t)B * SEQ * HD * 2);
  char* state0 = ws + off;
  unsigned short* h0r[4];
  for (int i = 0; i < 4; ++i) h0r[i] = (unsigned short*)take((size_t)B * HD * 2);
  unsigned short* h1b = (unsigned short*)take((size_t)B * HD * 2);
  unsigned short* rh0 = (unsigned short*)take((size_t)B * HD * 2);
  unsigned short* rh1 = (unsigned short*)take((size_t)B * HD * 2);
  unsigned* bar = (unsigned*)take((size_t)4 * 4096);
  size_t stateBytes = (size_t)((ws + off) - state0);

  {
    int n = B * SEQ * IN;
    hipLaunchKernelGGL(f32_to_bf16_k, dim3((n / 4 + 255) / 256), dim3(256), 0, stream,
                       (const float*)d_in[0], xbf, n);
  }

  {
    PackP pp;
    int s = 0;
    pp.seg[s++] = { (const float*)d_in[1],  wx0[0], HD, IN };
    pp.seg[s++] = { (const float*)d_in[4],  wx0[1], HD, IN };
    pp.seg[s++] = { (const float*)d_in[7],  wx0[2], HD, IN };
    pp.seg[s++] = { (const float*)d_in[3],  wh0[0], HD, HD };
    pp.seg[s++] = { (const float*)d_in[6],  wh0[1], HD, HD };
    pp.seg[s++] = { (const float*)d_in[9],  wh0[2], HD, HD };
    pp.seg[s++] = { (const float*)d_in[10], wx1[0], HD, HD };
    pp.seg[s++] = { (const float*)d_in[13], wx1[1], HD, HD };
    pp.seg[s++] = { (const float*)d_in[16], wx1[2], HD, HD };
    pp.seg[s++] = { (const float*)d_in[12], wh1[0], HD, HD };
    pp.seg[s++] = { (const float*)d_in[15], wh1[1], HD, HD };
    pp.seg[s++] = { (const float*)d_in[18], wh1[2], HD, HD };
    pp.seg[s++] = { (const float*)d_in[19], whyb, ODIM, HD };
    hipLaunchKernelGGL(pack_w, dim3(512, 13), dim3(256), 0, stream, pp);
  }

  hipMemsetAsync(state0, 0, stateBytes, stream);

  GruP P;
  P.xbf = xbf;
  for (int g = 0; g < 3; ++g) {
    P.wx[0][g] = wx0[g]; P.wh[0][g] = wh0[g];
    P.wx[1][g] = wx1[g]; P.wh[1][g] = wh1[g];
  }
  P.bx[0][0] = (const float*)d_in[2];  P.bx[0][1] = (const float*)d_in[5];  P.bx[0][2] = (const float*)d_in[8];
  P.bx[1][0] = (const float*)d_in[11]; P.bx[1][1] = (const float*)d_in[14]; P.bx[1][2] = (const float*)d_in[17];
  for (int i = 0; i < 4; ++i) P.h0b[i] = h0r[i];
  P.h1b = h1b;
  P.rh[0] = rh0; P.rh[1] = rh1;
  P.y1 = y1;
  P.outh = (float*)d_out + (size_t)B * SEQ * ODIM;
  P.bar = bar;

  hipLaunchKernelGGL(gru_persist, dim3(128), dim3(WGTH), 0, stream, P);

  hipLaunchKernelGGL(out_gemm, dim3((B * SEQ) / 64, ODIM / 64), dim3(256), 0, stream,
                     (const unsigned short*)y1, (const unsigned short*)whyb,
                     (const float*)d_in[20], (float*)d_out);
}